// Round 7
// baseline (184.616 us; speedup 1.0000x reference)
//
#include <hip/hip_runtime.h>

#define NB     8192
#define HDIM   64
#define SEQ    180
#define MT     16     // batch rows per block
#define SB     72     // bf16 LDS row stride: 144 B, 16B-aligned (SB=68 regressed: misaligned b128)
#define XSP    100    // xs prologue row stride (floats)

typedef __bf16 bf16x8 __attribute__((ext_vector_type(8)));
typedef __bf16 bf16x4 __attribute__((ext_vector_type(4)));
typedef float  f32x4  __attribute__((ext_vector_type(4)));

#define L2E 1.44269504088896340736f

__device__ __forceinline__ float tanh_f(float x) {
    float e = __builtin_amdgcn_exp2f((2.0f * L2E) * x);
    return 1.0f - 2.0f * __builtin_amdgcn_rcpf(1.0f + e);
}

#define MFMA __builtin_amdgcn_mfma_f32_16x16x32_bf16

// In-loop barrier: LDS-only drain (R17: neutral vs __syncthreads; kept so the
// deferred head's global store floats across barriers).
#define BAR_LDS() asm volatile("s_waitcnt lgkmcnt(0)\n\ts_barrier" ::: "memory")

// R21 = R20 + constant-folding into the MFMA operands (issue reduction):
//  - w_hh_R, w_hh_Z pre-scaled by -L2E and w_hh_N by +2*L2E before the bf16
//    cast (one-time prologue work), and each gate's FIRST MFMA seeds its
//    C-operand with the per-lane bias vector (cR4/cZ4/2L2E*b_hhN). The lane's
//    C reg r maps to gate col jb+r -- same vector the epilogue already used.
//  - Epilogue then reads eR=exp2(aR), eZ=exp2(aZ) straight off the
//    accumulators (tR/tZ FMAs gone, one dependency level shorter), mm
//    disappears, tN = rg*aN + cN4 is a single FMA (was mul+fma).
//  16 v-ops/wave-step removed; measured issue->period multiplier is ~2x
//  (R15->R18: -32 cy/wave issue gave -60 cy period), predict ~-64 cy period.
// History: R16 (dual-chain 1 blk/CU) regressed -- single wave can't out-issue
// two; R17 (no-vmcnt barrier) neutral; R19 (MT=8 + launch_bounds min-occ)
// regressed -- VGPR crushed to 64 -> spills, dummy rows double per-elem cost;
// R20 (setprio/sleep phase separation) neutral -- phase-lock not breakable.
// Period model: stall(~550) + 2x435 serialized burst; only issue cuts pay.
__global__ __launch_bounds__(256) void gru_all(
        const float* __restrict__ z, const int* __restrict__ labels,
        const float* __restrict__ embed_w, const float* __restrict__ fc_w,
        const float* __restrict__ fc_b, const float* __restrict__ w_hh,
        const float* __restrict__ b_ih, const float* __restrict__ b_hh,
        const float* __restrict__ out_w, const float* __restrict__ out_b,
        float* __restrict__ out) {
    __shared__ __align__(16) __bf16 hbuf[2][MT * SB];  // [buf] bf16(h)
    __shared__ __align__(16) float  xs[MT * XSP];      // h0 input [z|embed]

    const int t = threadIdx.x;
    const int w = t >> 6;          // wave 0..3
    const int l = t & 63;
    const int q = l >> 4;          // quad 0..3
    const int n16 = l & 15;
    const int jg = 16 * w + n16;   // W row this lane loads (A-frag m-index)
    const int jb = 16 * w + 4 * q; // first of the 4 h-cols this lane epilogues
    const int bbase = blockIdx.x * MT;

    // ---- prologue A: stage x = [z, embed(labels)] for 16 rows into LDS ----
    for (int c = t; c < MT * 24; c += 256) {    // 24 f32x4 chunks per row
        int m = c / 24, kk = (c % 24) * 4;
        f32x4 v;
        if (kk < 32) v = *(const f32x4*)(z + (size_t)(bbase + m) * 32 + kk);
        else         v = *(const f32x4*)(embed_w + labels[bbase + m] * 64 + (kk - 32));
        *(f32x4*)(xs + m * XSP + kk) = v;
    }

    // ---- persistent w_hh fragments, PRE-SCALED bf16 (MFMA A-operands) ----
    // A[m = n16][k = q*8+j + 32ks] = scale[g] * w_hh[g*64 + jg][k]
    // scale: R,Z = -L2E (so exp2(acc) = e^{-(W.h+b)}), N = +2*L2E.
    bf16x8 whi[3][2];
#pragma unroll
    for (int g = 0; g < 3; ++g) {
        const float wsc = (g == 2) ? (2.0f * L2E) : (-L2E);
        const float* pr = w_hh + (g * 64 + jg) * HDIM;
#pragma unroll
        for (int ks = 0; ks < 2; ++ks) {
            const float* p = pr + ks * 32 + q * 8;
            f32x4 va = *(const f32x4*)(p);
            f32x4 vb = *(const f32x4*)(p + 4);
#pragma unroll
            for (int j2 = 0; j2 < 4; ++j2) {
                whi[g][ks][j2]     = (__bf16)(va[j2] * wsc);
                whi[g][ks][4 + j2] = (__bf16)(vb[j2] * wsc);
            }
        }
    }

    // ---- output-head A fragments: A[m=n16][k] = out_w[n16][k] (n16<2 live) --
    bf16x8 obhi[2];
#pragma unroll
    for (int ks = 0; ks < 2; ++ks) {
        f32x4 va = {0.f, 0.f, 0.f, 0.f}, vb = {0.f, 0.f, 0.f, 0.f};
        if (n16 < 2) {
            va = *(const f32x4*)(out_w + n16 * 64 + ks * 32 + q * 8);
            vb = *(const f32x4*)(out_w + n16 * 64 + ks * 32 + q * 8 + 4);
        }
#pragma unroll
        for (int j2 = 0; j2 < 4; ++j2) {
            obhi[ks][j2]     = (__bf16)va[j2];
            obhi[ks][4 + j2] = (__bf16)vb[j2];
        }
    }
    // C/D bias by m-row (out-col): live rows m=0,1 sit at q==0, reg r=0,1
    const f32x4 obias = (q == 0) ? f32x4{out_b[0], out_b[1], 0.f, 0.f}
                                 : f32x4{0.f, 0.f, 0.f, 0.f};
    const f32x4 one4 = {1.f, 1.f, 1.f, 1.f};

    // every wave stores output for its 4 rows: q==0 lane, rows 4w..4w+3
    const bool ostorer = (q == 0) && ((n16 >> 2) == w);

    // per-lane gate constants over the lane's 4 cols jb..jb+3.
    // These now seed the gate MFMAs' C operands (C[m][n] = bias[m]; the
    // lane's C reg r is tile row 4q+r = gate col jb+r -- exact match).
    const f32x4 bihR = *(const f32x4*)(b_ih + jb);
    const f32x4 bhhR = *(const f32x4*)(b_hh + jb);
    const f32x4 bihZ = *(const f32x4*)(b_ih + 64 + jb);
    const f32x4 bhhZ = *(const f32x4*)(b_hh + 64 + jb);
    const f32x4 cR4 = (bihR + bhhR) * (-L2E);                       // C of R
    const f32x4 cZ4 = (bihZ + bhhZ) * (-L2E);                       // C of Z
    const f32x4 cNb = (*(const f32x4*)(b_hh + 128 + jb)) * (2.0f * L2E); // C of N
    const f32x4 cN4 = (*(const f32x4*)(b_ih + 128 + jb)) * (2.0f * L2E);

    const int rdoff = n16 * SB + q * 8;    // h B-frag offset (16B-aligned)
    const int wboff = n16 * SB + jb;       // state-write offset (8B-aligned)
    float* opb = out + (size_t)(bbase + n16) * (SEQ * 2);  // this lane's row

    __syncthreads();   // xs ready

    // ---- prologue B: h0 = tanh(fc_b + fc_w . x); lane -> row n16, 4 cols ----
    f32x4 hprev;
    {
        f32x4 a = *(const f32x4*)(fc_b + jb);
        for (int kc = 0; kc < 24; ++kc) {
            f32x4 xv = *(const f32x4*)(xs + n16 * XSP + kc * 4);
#pragma unroll
            for (int r = 0; r < 4; ++r) {
                f32x4 wv = *(const f32x4*)(fc_w + (size_t)(jb + r) * 96 + kc * 4);
                a[r] += wv[0] * xv[0] + wv[1] * xv[1] + wv[2] * xv[2] + wv[3] * xv[3];
            }
        }
        bf16x4 hp;
#pragma unroll
        for (int r = 0; r < 4; ++r) {
            hprev[r] = tanh_f(a[r]);
            hp[r] = (__bf16)hprev[r];
        }
        *(bf16x4*)(hbuf[0] + wboff) = hp;   // one ds_write_b64
    }
    __syncthreads();   // state 0 published in buf 0

    // Anti-phase the two co-resident blocks (i and i+256 share a CU) by
    // ~half a period; setprio below favors in-burst waves. (Both measured
    // neutral-to-slightly-positive; kept, harmless.)
    if ((blockIdx.x >> 8) & 1) __builtin_amdgcn_s_sleep(11);

    // previous step's b-frags for the deferred head (garbage first 2 iters;
    // computed unconditionally for wave balance, store is predicated)
    bf16x8 pb0 = {}, pb1 = {};

    for (int u = 0; u < SEQ / 4; ++u) {
#pragma unroll
        for (int s = 0; s < 4; ++s) {
            const int p = s & 1;
            const __bf16* Hh = hbuf[p];
            __bf16* Nh = hbuf[1 - p];

            // h B-frags of state i = 4u+s: B[k=q*8+j][n16] = h[n16][k]
            bf16x8 b0 = *(const bf16x8*)(Hh + rdoff);
            bf16x8 b1 = *(const bf16x8*)(Hh + rdoff + 32);

            // deferred output head (state i-1 -> out row i-2): register-only
            // MFMAs fill the ds_read lgkm-wait shadow right after the barrier
            {
                f32x4 o = obias;
                o = MFMA(obhi[0], pb0, o, 0, 0, 0);
                o = MFMA(obhi[1], pb1, o, 0, 0, 0);
                if ((u > 0 || s >= 2) && ostorer)
                    *(float2*)(opb + (8 * u + 2 * s - 4)) = make_float2(o[0], o[1]);
            }

            __builtin_amdgcn_s_setprio(1);

            // gates, bias-seeded and pre-scaled: acc = scale*(W.h + b_hh-part)
            // aR = -L2E*(W_R.h + bR), aZ = -L2E*(W_Z.h + bZ),
            // aN =  2L2E*(W_N.h + b_hhN)
            f32x4 aR, aZ, aN;
            aR = MFMA(whi[0][0], b0, cR4, 0, 0, 0);
            aZ = MFMA(whi[1][0], b0, cZ4, 0, 0, 0);
            aN = MFMA(whi[2][0], b0, cNb, 0, 0, 0);
            aR = MFMA(whi[0][1], b1, aR, 0, 0, 0);
            aZ = MFMA(whi[1][1], b1, aZ, 0, 0, 0);
            aN = MFMA(whi[2][1], b1, aN, 0, 0, 0);

            // fused epilogue: exp2 straight off the accumulators.
            // h' = [h*(eN+1) + eZ*(eN-1)] / [(eN+1)(1+eZ)]
            f32x4 eR, eZ;
#pragma unroll
            for (int r = 0; r < 4; ++r) {
                eR[r] = __builtin_amdgcn_exp2f(aR[r]);
                eZ[r] = __builtin_amdgcn_exp2f(aZ[r]);
            }
            f32x4 A = eR + one4;
            f32x4 rg;
#pragma unroll
            for (int r = 0; r < 4; ++r) rg[r] = __builtin_amdgcn_rcpf(A[r]);
            f32x4 tN = rg * aN + cN4;        // aN already 2L2E*(h_n-part)
            f32x4 eN;
#pragma unroll
            for (int r = 0; r < 4; ++r) eN[r] = __builtin_amdgcn_exp2f(tN[r]);
            f32x4 wz = eZ + one4;            // 1 + eZ
            f32x4 pz = eZ + hprev;           // eZ + h
            f32x4 qz = hprev - eZ;           // h - eZ
            f32x4 Nst = eN * pz + qz;        // h*(eN+1) + eZ*(eN-1)
            f32x4 Dst = eN * wz + wz;        // (eN+1)*(1+eZ)
            f32x4 rD;
#pragma unroll
            for (int r = 0; r < 4; ++r) rD[r] = __builtin_amdgcn_rcpf(Dst[r]);
            f32x4 hn = Nst * rD;             // exact fp32 carry
            hprev = hn;
            bf16x4 hp;
#pragma unroll
            for (int r = 0; r < 4; ++r) hp[r] = (__bf16)hn[r];
            *(bf16x4*)(Nh + wboff) = hp;     // one ds_write_b64

            __builtin_amdgcn_s_setprio(0);

            pb0 = b0; pb1 = b1;              // renamed, not copied (unroll 4)

            BAR_LDS();   // state i+1 published (LDS-only drain; stores float)
        }
    }

    // tail: deferred head of state 179 (pb) -> row 178, then state 180 -> 179
    {
        f32x4 o = obias;
        o = MFMA(obhi[0], pb0, o, 0, 0, 0);
        o = MFMA(obhi[1], pb1, o, 0, 0, 0);
        if (ostorer)
            *(float2*)(opb + (SEQ - 2) * 2) = make_float2(o[0], o[1]);

        const __bf16* Hh = hbuf[0];
        bf16x8 b0 = *(const bf16x8*)(Hh + rdoff);
        bf16x8 b1 = *(const bf16x8*)(Hh + rdoff + 32);
        f32x4 o2 = obias;
        o2 = MFMA(obhi[0], b0, o2, 0, 0, 0);
        o2 = MFMA(obhi[1], b1, o2, 0, 0, 0);
        if (ostorer)
            *(float2*)(opb + (SEQ - 1) * 2) = make_float2(o2[0], o2[1]);
    }
}

extern "C" void kernel_launch(void* const* d_in, const int* in_sizes, int n_in,
                              void* d_out, int out_size, void* d_ws, size_t ws_size,
                              hipStream_t stream) {
    (void)in_sizes; (void)n_in; (void)out_size; (void)d_ws; (void)ws_size;
    const float* z       = (const float*)d_in[0];
    const int*   labels  = (const int*)d_in[1];
    const float* embed_w = (const float*)d_in[2];
    const float* fc_w    = (const float*)d_in[3];
    const float* fc_b    = (const float*)d_in[4];
    // d_in[5] = w_ih: unused (GRU input is all zeros; b_ih carries the effect)
    const float* w_hh    = (const float*)d_in[6];
    const float* b_ih    = (const float*)d_in[7];
    const float* b_hh    = (const float*)d_in[8];
    const float* out_w   = (const float*)d_in[9];
    const float* out_b   = (const float*)d_in[10];
    float* out = (float*)d_out;

    gru_all<<<NB / MT, 256, 0, stream>>>(z, labels, embed_w, fc_w, fc_b,
                                         w_hh, b_ih, b_hh, out_w, out_b, out);
}

// Round 8
// 173.568 us; speedup vs baseline: 1.0637x; 1.0637x over previous
//
#include <hip/hip_runtime.h>

#define NB     8192
#define HDIM   64
#define SEQ    180
#define MT     16     // batch rows per chain
#define NC     2      // chains per block (advance together, one barrier)
#define SB     72     // bf16 LDS row stride: 144 B, 16B-aligned
#define XSP    100    // xs prologue row stride (floats)

typedef __bf16 bf16x8 __attribute__((ext_vector_type(8)));
typedef __bf16 bf16x4 __attribute__((ext_vector_type(4)));
typedef float  f32x4  __attribute__((ext_vector_type(4)));

#define L2E 1.44269504088896340736f

__device__ __forceinline__ float tanh_f(float x) {
    float e = __builtin_amdgcn_exp2f((2.0f * L2E) * x);
    return 1.0f - 2.0f * __builtin_amdgcn_rcpf(1.0f + e);
}

#define MFMA __builtin_amdgcn_mfma_f32_16x16x32_bf16

// In-loop barrier: LDS-only drain (R17: neutral vs __syncthreads; lets the
// head's global stores float across barriers).
#define BAR_LDS() asm volatile("s_waitcnt lgkmcnt(0)\n\ts_barrier" ::: "memory")

// R22 = R16's dual-chain/1-block-per-CU structure, EXECUTED RIGHT:
//  - R16 failed (131us) because its two chains' epilogues were emitted
//    serially (two gru_epi calls): an in-order wave stalls on chain A's
//    trans-dependency with chain B's instructions stuck behind it in program
//    order. VALUBusy 50% x period showed issue ~2x expected -- serialization,
//    not a structural limit.
//  - Here every epilogue stage is hand-interleaved A,B,A,B (trans loops issue
//    16/8/8/8 independent ops back-to-back), so each chain's exp2/rcp latency
//    hides under the other's issue. Plus R18's deferred head in the ds_read
//    shadow and R18's fused 5-trans math (bit-identical per chain).
//  - 1 block/CU (grid 256, 4 waves): no partner-block phase lock (R20's
//    setprio/sleep attempts showed it can't be broken at 2 blocks/CU), no
//    128-VGPR occupancy cliff (R21: 132 VGPR halved residency, 136us).
// Sum: 2 chains x 435cy issue, stalls mutually covered -> period ~1050-1150cy
// per 32 rows vs R20's 1413cy per 32 rows.
__global__ __launch_bounds__(256) void gru_all(
        const float* __restrict__ z, const int* __restrict__ labels,
        const float* __restrict__ embed_w, const float* __restrict__ fc_w,
        const float* __restrict__ fc_b, const float* __restrict__ w_hh,
        const float* __restrict__ b_ih, const float* __restrict__ b_hh,
        const float* __restrict__ out_w, const float* __restrict__ out_b,
        float* __restrict__ out) {
    __shared__ __align__(16) __bf16 hbuf[NC][2][MT * SB];  // [chain][buf]
    __shared__ __align__(16) float  xs[NC * MT * XSP];     // h0 input [z|embed]

    const int t = threadIdx.x;
    const int w = t >> 6;          // wave 0..3
    const int l = t & 63;
    const int q = l >> 4;          // quad 0..3
    const int n16 = l & 15;
    const int jg = 16 * w + n16;   // W row this lane loads (A-frag m-index)
    const int jb = 16 * w + 4 * q; // first of the 4 h-cols this lane epilogues
    const int bbase = blockIdx.x * (NC * MT);

    // ---- prologue A: stage x = [z, embed(labels)] for 32 rows into LDS ----
    for (int c = t; c < NC * MT * 24; c += 256) {   // 24 f32x4 chunks per row
        int m = c / 24, kk = (c % 24) * 4;
        f32x4 v;
        if (kk < 32) v = *(const f32x4*)(z + (size_t)(bbase + m) * 32 + kk);
        else         v = *(const f32x4*)(embed_w + labels[bbase + m] * 64 + (kk - 32));
        *(f32x4*)(xs + m * XSP + kk) = v;
    }

    // ---- persistent w_hh fragments, plain bf16 (MFMA A-operands) ----
    // A[m = n16][k = q*8+j + 32ks] = w_hh[g*64 + jg][k]  (shared by chains)
    bf16x8 whi[3][2];
#pragma unroll
    for (int g = 0; g < 3; ++g) {
        const float* pr = w_hh + (g * 64 + jg) * HDIM;
#pragma unroll
        for (int ks = 0; ks < 2; ++ks) {
            const float* p = pr + ks * 32 + q * 8;
            f32x4 va = *(const f32x4*)(p);
            f32x4 vb = *(const f32x4*)(p + 4);
#pragma unroll
            for (int j2 = 0; j2 < 4; ++j2) {
                whi[g][ks][j2]     = (__bf16)va[j2];
                whi[g][ks][4 + j2] = (__bf16)vb[j2];
            }
        }
    }

    // ---- output-head A fragments: A[m=n16][k] = out_w[n16][k] (n16<2 live) --
    bf16x8 obhi[2];
#pragma unroll
    for (int ks = 0; ks < 2; ++ks) {
        f32x4 va = {0.f, 0.f, 0.f, 0.f}, vb = {0.f, 0.f, 0.f, 0.f};
        if (n16 < 2) {
            va = *(const f32x4*)(out_w + n16 * 64 + ks * 32 + q * 8);
            vb = *(const f32x4*)(out_w + n16 * 64 + ks * 32 + q * 8 + 4);
        }
#pragma unroll
        for (int j2 = 0; j2 < 4; ++j2) {
            obhi[ks][j2]     = (__bf16)va[j2];
            obhi[ks][4 + j2] = (__bf16)vb[j2];
        }
    }
    const f32x4 obias = (q == 0) ? f32x4{out_b[0], out_b[1], 0.f, 0.f}
                                 : f32x4{0.f, 0.f, 0.f, 0.f};
    const f32x4 kZ = {0.f, 0.f, 0.f, 0.f};
    const f32x4 one4 = {1.f, 1.f, 1.f, 1.f};

    // all waves compute heads (identical streams); each stores its 4 rows/chain
    const bool ostorer = (q == 0) && ((n16 >> 2) == w);

    // per-lane gate constants over the lane's 4 cols jb..jb+3 (chain-shared)
    const f32x4 bihR = *(const f32x4*)(b_ih + jb);
    const f32x4 bhhR = *(const f32x4*)(b_hh + jb);
    const f32x4 bihZ = *(const f32x4*)(b_ih + 64 + jb);
    const f32x4 bhhZ = *(const f32x4*)(b_hh + 64 + jb);
    const f32x4 cR4 = (bihR + bhhR) * (-L2E);
    const f32x4 cZ4 = (bihZ + bhhZ) * (-L2E);
    const f32x4 bn4 = *(const f32x4*)(b_hh + 128 + jb);
    const f32x4 cN4 = (*(const f32x4*)(b_ih + 128 + jb)) * (2.0f * L2E);

    const int rdoff = n16 * SB + q * 8;    // h B-frag offset (16B-aligned)
    const int wboff = n16 * SB + jb;       // state-write offset (8B-aligned)
    float* opbA = out + (size_t)(bbase + n16) * (SEQ * 2);
    float* opbB = out + (size_t)(bbase + MT + n16) * (SEQ * 2);

    __syncthreads();   // xs ready

    // ---- prologue B: h0 for BOTH chains (fc_w row loads shared) ----
    f32x4 hpA, hpB;
    {
        f32x4 aA = *(const f32x4*)(fc_b + jb);
        f32x4 aB = aA;
        for (int kc = 0; kc < 24; ++kc) {
            f32x4 xvA = *(const f32x4*)(xs + n16 * XSP + kc * 4);
            f32x4 xvB = *(const f32x4*)(xs + (MT + n16) * XSP + kc * 4);
#pragma unroll
            for (int r = 0; r < 4; ++r) {
                f32x4 wv = *(const f32x4*)(fc_w + (size_t)(jb + r) * 96 + kc * 4);
                aA[r] += wv[0] * xvA[0] + wv[1] * xvA[1] + wv[2] * xvA[2] + wv[3] * xvA[3];
                aB[r] += wv[0] * xvB[0] + wv[1] * xvB[1] + wv[2] * xvB[2] + wv[3] * xvB[3];
            }
        }
        bf16x4 ha, hb;
#pragma unroll
        for (int r = 0; r < 4; ++r) {
            hpA[r] = tanh_f(aA[r]); ha[r] = (__bf16)hpA[r];
            hpB[r] = tanh_f(aB[r]); hb[r] = (__bf16)hpB[r];
        }
        *(bf16x4*)(hbuf[0][0] + wboff) = ha;
        *(bf16x4*)(hbuf[1][0] + wboff) = hb;
    }
    __syncthreads();   // state 0 published in buf 0 for both chains

    // previous step's b-frags for the deferred heads (garbage first 2 iters;
    // computed unconditionally, stores predicated)
    bf16x8 paA0 = {}, paA1 = {}, paB0 = {}, paB1 = {};

    for (int u = 0; u < SEQ / 4; ++u) {
#pragma unroll
        for (int s = 0; s < 4; ++s) {
            const int p = s & 1;
            const __bf16* HA = hbuf[0][p];
            __bf16*       NA = hbuf[0][1 - p];
            const __bf16* HB = hbuf[1][p];
            __bf16*      NhB = hbuf[1][1 - p];

            // issue all 4 state reads up front (step i = 4u+s)
            bf16x8 a0 = *(const bf16x8*)(HA + rdoff);
            bf16x8 a1 = *(const bf16x8*)(HA + rdoff + 32);
            bf16x8 c0 = *(const bf16x8*)(HB + rdoff);
            bf16x8 c1 = *(const bf16x8*)(HB + rdoff + 32);

            // deferred heads (state i-1 -> out row i-2): register-only MFMAs
            // in the ds_read shadow
            {
                f32x4 oA = obias, oB = obias;
                oA = MFMA(obhi[0], paA0, oA, 0, 0, 0);
                oB = MFMA(obhi[0], paB0, oB, 0, 0, 0);
                oA = MFMA(obhi[1], paA1, oA, 0, 0, 0);
                oB = MFMA(obhi[1], paB1, oB, 0, 0, 0);
                if ((u > 0 || s >= 2) && ostorer) {
                    *(float2*)(opbA + (8 * u + 2 * s - 4)) = make_float2(oA[0], oA[1]);
                    *(float2*)(opbB + (8 * u + 2 * s - 4)) = make_float2(oB[0], oB[1]);
                }
            }

            // gates for both chains, interleaved (independent MFMAs)
            f32x4 aRA = MFMA(whi[0][0], a0, kZ, 0, 0, 0);
            f32x4 aRB = MFMA(whi[0][0], c0, kZ, 0, 0, 0);
            f32x4 aZA = MFMA(whi[1][0], a0, kZ, 0, 0, 0);
            f32x4 aZB = MFMA(whi[1][0], c0, kZ, 0, 0, 0);
            f32x4 aNA = MFMA(whi[2][0], a0, kZ, 0, 0, 0);
            f32x4 aNB = MFMA(whi[2][0], c0, kZ, 0, 0, 0);
            aRA = MFMA(whi[0][1], a1, aRA, 0, 0, 0);
            aRB = MFMA(whi[0][1], c1, aRB, 0, 0, 0);
            aZA = MFMA(whi[1][1], a1, aZA, 0, 0, 0);
            aZB = MFMA(whi[1][1], c1, aZB, 0, 0, 0);
            aNA = MFMA(whi[2][1], a1, aNA, 0, 0, 0);
            aNB = MFMA(whi[2][1], c1, aNB, 0, 0, 0);

            // ---- fused epilogue, STAGE-INTERLEAVED across chains ----
            // h' = [h*(eN+1) + eZ*(eN-1)] / [(eN+1)(1+eZ)]  (per chain)
            f32x4 tRA = aRA * (-L2E) + cR4;
            f32x4 tRB = aRB * (-L2E) + cR4;
            f32x4 tZA = aZA * (-L2E) + cZ4;
            f32x4 tZB = aZB * (-L2E) + cZ4;
            f32x4 eRA, eRB, eZA, eZB;
#pragma unroll
            for (int r = 0; r < 4; ++r) {
                eRA[r] = __builtin_amdgcn_exp2f(tRA[r]);
                eRB[r] = __builtin_amdgcn_exp2f(tRB[r]);
                eZA[r] = __builtin_amdgcn_exp2f(tZA[r]);
                eZB[r] = __builtin_amdgcn_exp2f(tZB[r]);
            }
            f32x4 AA = eRA + one4;
            f32x4 AB = eRB + one4;
            f32x4 rgA, rgB;
#pragma unroll
            for (int r = 0; r < 4; ++r) {
                rgA[r] = __builtin_amdgcn_rcpf(AA[r]);
                rgB[r] = __builtin_amdgcn_rcpf(AB[r]);
            }
            f32x4 mmA = aNA + bn4;
            f32x4 mmB = aNB + bn4;
            f32x4 tNA = (rgA * mmA) * (2.0f * L2E) + cN4;
            f32x4 tNB = (rgB * mmB) * (2.0f * L2E) + cN4;
            f32x4 eNA, eNB;
#pragma unroll
            for (int r = 0; r < 4; ++r) {
                eNA[r] = __builtin_amdgcn_exp2f(tNA[r]);
                eNB[r] = __builtin_amdgcn_exp2f(tNB[r]);
            }
            f32x4 wzA = eZA + one4,  wzB = eZB + one4;
            f32x4 pzA = eZA + hpA,   pzB = eZB + hpB;
            f32x4 qzA = hpA - eZA,   qzB = hpB - eZB;
            f32x4 NsA = eNA * pzA + qzA;
            f32x4 NsB = eNB * pzB + qzB;
            f32x4 DsA = eNA * wzA + wzA;
            f32x4 DsB = eNB * wzB + wzB;
            f32x4 rDA, rDB;
#pragma unroll
            for (int r = 0; r < 4; ++r) {
                rDA[r] = __builtin_amdgcn_rcpf(DsA[r]);
                rDB[r] = __builtin_amdgcn_rcpf(DsB[r]);
            }
            f32x4 hnA = NsA * rDA;           // exact fp32 carry
            f32x4 hnB = NsB * rDB;
            hpA = hnA; hpB = hnB;
            bf16x4 ha, hb;
#pragma unroll
            for (int r = 0; r < 4; ++r) {
                ha[r] = (__bf16)hnA[r];
                hb[r] = (__bf16)hnB[r];
            }
            *(bf16x4*)(NA  + wboff) = ha;    // one ds_write_b64 each
            *(bf16x4*)(NhB + wboff) = hb;

            paA0 = a0; paA1 = a1; paB0 = c0; paB1 = c1;  // renamed (unroll 4)

            BAR_LDS();   // states i+1 (both chains) published
        }
    }

    // tail: deferred heads of state 179 -> row 178, then state 180 -> row 179
    {
        f32x4 oA = obias, oB = obias;
        oA = MFMA(obhi[0], paA0, oA, 0, 0, 0);
        oB = MFMA(obhi[0], paB0, oB, 0, 0, 0);
        oA = MFMA(obhi[1], paA1, oA, 0, 0, 0);
        oB = MFMA(obhi[1], paB1, oB, 0, 0, 0);
        if (ostorer) {
            *(float2*)(opbA + (SEQ - 2) * 2) = make_float2(oA[0], oA[1]);
            *(float2*)(opbB + (SEQ - 2) * 2) = make_float2(oB[0], oB[1]);
        }

        bf16x8 a0 = *(const bf16x8*)(hbuf[0][0] + rdoff);
        bf16x8 a1 = *(const bf16x8*)(hbuf[0][0] + rdoff + 32);
        bf16x8 c0 = *(const bf16x8*)(hbuf[1][0] + rdoff);
        bf16x8 c1 = *(const bf16x8*)(hbuf[1][0] + rdoff + 32);
        f32x4 o2A = obias, o2B = obias;
        o2A = MFMA(obhi[0], a0, o2A, 0, 0, 0);
        o2B = MFMA(obhi[0], c0, o2B, 0, 0, 0);
        o2A = MFMA(obhi[1], a1, o2A, 0, 0, 0);
        o2B = MFMA(obhi[1], c1, o2B, 0, 0, 0);
        if (ostorer) {
            *(float2*)(opbA + (SEQ - 1) * 2) = make_float2(o2A[0], o2A[1]);
            *(float2*)(opbB + (SEQ - 1) * 2) = make_float2(o2B[0], o2B[1]);
        }
    }
}

extern "C" void kernel_launch(void* const* d_in, const int* in_sizes, int n_in,
                              void* d_out, int out_size, void* d_ws, size_t ws_size,
                              hipStream_t stream) {
    (void)in_sizes; (void)n_in; (void)out_size; (void)d_ws; (void)ws_size;
    const float* z       = (const float*)d_in[0];
    const int*   labels  = (const int*)d_in[1];
    const float* embed_w = (const float*)d_in[2];
    const float* fc_w    = (const float*)d_in[3];
    const float* fc_b    = (const float*)d_in[4];
    // d_in[5] = w_ih: unused (GRU input is all zeros; b_ih carries the effect)
    const float* w_hh    = (const float*)d_in[6];
    const float* b_ih    = (const float*)d_in[7];
    const float* b_hh    = (const float*)d_in[8];
    const float* out_w   = (const float*)d_in[9];
    const float* out_b   = (const float*)d_in[10];
    float* out = (float*)d_out;

    gru_all<<<NB / (NC * MT), 256, 0, stream>>>(z, labels, embed_w, fc_w, fc_b,
                                                w_hh, b_ih, b_hh, out_w, out_b, out);
}